// Round 6
// baseline (575.595 us; speedup 1.0000x reference)
//
#include <hip/hip_runtime.h>

// ============================================================================
// Attention_14362370637857 on MI355X (gfx950).
// B=2, S=2048, D_MODEL=2048, NH=32, NKV=8 (GQA rep=4), DH=64.
//
// Pipeline:
//   1) detect_kernel   : dtype sniff (bf16 vs f32 inputs) -> flag
//   2) convert_kernel  : residual,W_Q,W_K,W_V -> canonical bf16 in ws
//   3) qkv_gemm_kernel : R[4096,2048] x W^T -> q (in d_out), k, v
//   4) vt_kernel       : v [b,p,h] -> vT [b,h,p]
//   5) attn_kernel v6  : causal flash attention, GQA kv-group blocks
//   6) transpose_kernel: W_O -> W_O^T (flag-aware read)
//   7) out_gemm_kernel : abuf x W_O^T -> d_out (bf16 or f32 per flag)
//
// attn v6: block = 4 waves = the 4 q-heads of ONE kv group over the SAME 32
// q-rows -> K staged in LDS once per tile (double-buffered async_ld16, one
// barrier/iter) and reused by all 4 waves; V^T frags direct global->regs
// hoisted (L2-local thanks to XCD pinning: grid.x = b*8+kv so linear%8 = kv).
// Identical per-wave causal trip counts; P transit + line-coalesced epilogue
// as verified in R3/R5. LDS = 16K (K dbuf) + 16K (P) = 32 KB.
// ============================================================================

typedef __attribute__((ext_vector_type(8))) short short8;   // 8 bf16
typedef __attribute__((ext_vector_type(4))) short short4v;  // 4 bf16 = 8B
typedef __attribute__((ext_vector_type(4))) float f32x4;    // MFMA 16x16 C/D

__device__ __forceinline__ short f2bs(float f) {  // f32 -> bf16 bits, RNE
  unsigned u = __float_as_uint(f);
  u = (u + 0x7fffu + ((u >> 16) & 1u)) >> 16;
  return (short)u;
}
__device__ __forceinline__ float bs2f(short s) {  // bf16 bits -> f32
  return __uint_as_float(((unsigned)(unsigned short)s) << 16);
}

__device__ __forceinline__ void async_ld16(const void* g, void* l) {
  __builtin_amdgcn_global_load_lds((__attribute__((address_space(1))) void*)(g),
                                   (__attribute__((address_space(3))) void*)(l),
                                   16, 0, 0);
}

// ----------------------------------------------------------------------------
__global__ __launch_bounds__(256) void detect_kernel(const short* __restrict__ r,
                                                     int* __restrict__ flag) {
  __shared__ int bad;
  if (threadIdx.x == 0) bad = 0;
  __syncthreads();
  int mybad = 0;
#pragma unroll
  for (int i = 0; i < 16; ++i) {
    float x = bs2f(r[threadIdx.x + i * 256]);
    if (!(fabsf(x) < 100.0f)) mybad = 1;
  }
  if (mybad) atomicOr(&bad, 1);
  __syncthreads();
  if (threadIdx.x == 0) *flag = bad;
}

// ----------------------------------------------------------------------------
__global__ __launch_bounds__(256) void convert_kernel(
    const void* __restrict__ s0, const void* __restrict__ s1,
    const void* __restrict__ s2, const void* __restrict__ s3,
    short* __restrict__ d0, short* __restrict__ d1, short* __restrict__ d2,
    short* __restrict__ d3, const int* __restrict__ flag) {
  long off = (long)blockIdx.x * 256 + threadIdx.x;
  const void* src;
  short* dst;
  if (off < 1048576) {
    src = s0; dst = d0;
  } else if ((off -= 1048576) < 524288) {
    src = s1; dst = d1;
  } else if ((off -= 524288) < 131072) {
    src = s2; dst = d2;
  } else {
    off -= 131072; src = s3; dst = d3;
  }
  const long e = off * 8;
  short8 v;
  if (*flag) {
    const float* f = (const float*)src + e;
    const f32x4 a = *(const f32x4*)(f);
    const f32x4 b = *(const f32x4*)(f + 4);
#pragma unroll
    for (int j = 0; j < 4; ++j) {
      v[j] = f2bs(a[j]);
      v[4 + j] = f2bs(b[j]);
    }
  } else {
    v = *(const short8*)((const short*)src + e);
  }
  *(short8*)(dst + e) = v;
}

// ----------------------------------------------------------------------------
// C[M,N] = A[M,K] * B[N,K]^T (row-major bf16), 128x128 tile, BK=32.
// ----------------------------------------------------------------------------
__device__ __forceinline__ void gemm128(const short* __restrict__ A, int lda,
                                        const short* __restrict__ B, int ldb,
                                        void* __restrict__ C, int ldc,
                                        int rowBase, int colBase, int K,
                                        short* As, short* Bs, int outF32) {
  const int t = threadIdx.x;
  const int wave = t >> 6;
  const int lane = t & 63;
  const int quad = lane >> 4;
  const int m16 = lane & 15;
  const int sRow = t >> 2;
  const int sOff = (t & 3) * 8;
  const int wr = (wave >> 1) * 64;
  const int wc = (wave & 1) * 64;

  const short* A0 = A + (size_t)(rowBase + sRow) * lda + sOff;
  const short* A1 = A0 + (size_t)64 * lda;
  const short* B0 = B + (size_t)(colBase + sRow) * ldb + sOff;
  const short* B1 = B0 + (size_t)64 * ldb;

  short* ldsA0 = As + wave * 512;
  short* ldsA1 = As + 2048 + wave * 512;
  short* ldsB0 = Bs + wave * 512;
  short* ldsB1 = Bs + 2048 + wave * 512;

  f32x4 acc[4][4] = {};

  const int nK = K >> 5;
  for (int kt = 0; kt < nK; ++kt) {
    __syncthreads();
    const int ko = kt * 32;
    async_ld16(A0 + ko, ldsA0);
    async_ld16(A1 + ko, ldsA1);
    async_ld16(B0 + ko, ldsB0);
    async_ld16(B1 + ko, ldsB1);
    __syncthreads();

    short8 af[4], bfr[4];
#pragma unroll
    for (int i = 0; i < 4; ++i)
      af[i] = *(const short8*)(As + (wr + i * 16 + m16) * 32 + quad * 8);
#pragma unroll
    for (int i = 0; i < 4; ++i)
      bfr[i] = *(const short8*)(Bs + (wc + i * 16 + m16) * 32 + quad * 8);
#pragma unroll
    for (int i = 0; i < 4; ++i)
#pragma unroll
      for (int j = 0; j < 4; ++j)
        acc[i][j] = __builtin_amdgcn_mfma_f32_16x16x32_bf16(af[i], bfr[j],
                                                            acc[i][j], 0, 0, 0);
  }

#pragma unroll
  for (int i = 0; i < 4; ++i)
#pragma unroll
    for (int j = 0; j < 4; ++j)
#pragma unroll
      for (int r = 0; r < 4; ++r) {
        const int row = rowBase + wr + i * 16 + quad * 4 + r;
        const int col = colBase + wc + j * 16 + m16;
        const size_t idx = (size_t)row * ldc + col;
        if (outF32)
          ((float*)C)[idx] = acc[i][j][r];
        else
          ((short*)C)[idx] = f2bs(acc[i][j][r]);
      }
}

__global__ __launch_bounds__(256) void qkv_gemm_kernel(
    const short* __restrict__ R, const short* __restrict__ WQ,
    const short* __restrict__ WK, const short* __restrict__ WV,
    short* __restrict__ q, short* __restrict__ k, short* __restrict__ v) {
  __shared__ __align__(16) short As[128 * 32];
  __shared__ __align__(16) short Bs[128 * 32];
  const int ct = blockIdx.x;
  const int rowBase = blockIdx.y * 128;
  const short* B;
  short* C;
  int colBase, ldc;
  if (ct < 16) {
    B = WQ; C = q; colBase = ct * 128; ldc = 2048;
  } else if (ct < 20) {
    B = WK; C = k; colBase = (ct - 16) * 128; ldc = 512;
  } else {
    B = WV; C = v; colBase = (ct - 20) * 128; ldc = 512;
  }
  gemm128(R, 2048, B, 2048, C, ldc, rowBase, colBase, 2048, As, Bs, 0);
}

__global__ __launch_bounds__(256) void out_gemm_kernel(
    const short* __restrict__ A, const short* __restrict__ Bt,
    void* __restrict__ C, const int* __restrict__ flag) {
  __shared__ __align__(16) short As[128 * 32];
  __shared__ __align__(16) short Bs[128 * 32];
  const int outF32 = *flag;
  gemm128(A, 2048, Bt, 2048, C, 2048, blockIdx.y * 128, blockIdx.x * 128, 2048,
          As, Bs, outF32);
}

// ----------------------------------------------------------------------------
// W_O [2048,2048] -> W_O^T, flag-aware source dtype.
// ----------------------------------------------------------------------------
__global__ __launch_bounds__(256) void transpose_kernel(
    const void* __restrict__ in, short* __restrict__ out,
    const int* __restrict__ flag) {
  __shared__ short tile[64][65];
  const int bx = blockIdx.x, by = blockIdx.y;
  const int tx = threadIdx.x & 63, ty = threadIdx.x >> 6;
  const int isf = *flag;
#pragma unroll
  for (int i = 0; i < 16; ++i) {
    const int r = ty + i * 4;
    const size_t idx = (size_t)(by * 64 + r) * 2048 + bx * 64 + tx;
    tile[r][tx] = isf ? f2bs(((const float*)in)[idx]) : ((const short*)in)[idx];
  }
  __syncthreads();
#pragma unroll
  for (int i = 0; i < 16; ++i) {
    const int r = ty + i * 4;
    out[(size_t)(bx * 64 + r) * 2048 + by * 64 + tx] = tile[tx][r];
  }
}

// ----------------------------------------------------------------------------
// v [2,2048,512] -> vT [2,512,2048]
// ----------------------------------------------------------------------------
__global__ __launch_bounds__(256) void vt_kernel(const short* __restrict__ v,
                                                 short* __restrict__ vt) {
  __shared__ short tile[64][65];
  const int hb = blockIdx.x * 64, pb = blockIdx.y * 64, b = blockIdx.z;
  const int tx = threadIdx.x & 63, ty = threadIdx.x >> 6;
#pragma unroll
  for (int i = 0; i < 16; ++i) {
    const int r = ty + i * 4;
    tile[r][tx] = v[((size_t)(b * 2048 + pb + r)) * 512 + hb + tx];
  }
  __syncthreads();
#pragma unroll
  for (int i = 0; i < 16; ++i) {
    const int r = ty + i * 4;
    vt[((size_t)(b * 512 + hb + r)) * 2048 + pb + tx] = tile[tx][r];
  }
}

// ----------------------------------------------------------------------------
// Causal flash attention v6: GQA kv-group blocks.
// Grid (16, 64): x = b*8+kv (XCD-pinned: linear%8 = kv), y -> qc = 63-y.
// Block = 4 waves; wave w = q-head kv*4+w; ALL waves share q-rows
// [qc*32, qc*32+32) and the LDS-staged K tile. K double-buffered via
// async_ld16 (one barrier/iter, prefetch after barrier); V^T frags direct
// global->regs, hoisted (L2-local per XCD). Per 64-key tile:
//   S^T[key][qrow] = K(A-frags, LDS) x Q^T(B-frags, regs)
//   O^T[h][qrow]  += V^T(A-frags, global) x P^T(B-frags via LDS transit)
// ----------------------------------------------------------------------------
__global__ __launch_bounds__(256, 4) void attn_kernel(
    const short* __restrict__ qbuf, const short* __restrict__ kbuf,
    const short* __restrict__ vtb, short* __restrict__ obuf) {
  __shared__ __align__(16) short Ks[2][64 * 64];  // 16 KB K double-buffer
  __shared__ __align__(16) short Pb[4][32 * 64];  // 16 KB per-wave P transit

  const int b = blockIdx.x >> 3;
  const int kv = blockIdx.x & 7;
  const int qc = 63 - blockIdx.y;  // long-first dispatch
  const int t = threadIdx.x;
  const int wave = t >> 6;
  const int hd = kv * 4 + wave;
  const int lane = t & 63;
  const int quad = lane >> 4;
  const int col = lane & 15;
  const int rb0 = qc * 32;

  // Q B-frags: B[k=quad*8+j (+32*kh)][n=col] = Q[qrow][h]
  short8 qf[2][2];
#pragma unroll
  for (int nt = 0; nt < 2; ++nt) {
    const int qr = rb0 + nt * 16 + col;
    const short* qp = qbuf + ((size_t)(b * 2048 + qr)) * 2048 + hd * 64 + quad * 8;
    qf[nt][0] = *(const short8*)(qp);
    qf[nt][1] = *(const short8*)(qp + 32);
  }

  float mloc[2] = {-3.0e38f, -3.0e38f};
  float lloc[2] = {0.f, 0.f};
  f32x4 oacc[2][4] = {};

  short* P = &Pb[wave][0];
  const int swz = 4 * (col & 3);  // P chunk swizzle

  // K staging (R3-verified): thread t covers rows t>>3 and +32, chunk t&7,
  // LDS row r chunk c holds global chunk c^(r&7).
  const int sRow = t >> 3;
  const int sPos = t & 7;
  const int r1 = sRow + 32;
  const short* kRow0 = kbuf + ((size_t)(b * 2048 + sRow)) * 512 + kv * 64 +
                       ((sPos ^ (sRow & 7)) * 8);
  const short* kRow1 = kbuf + ((size_t)(b * 2048 + r1)) * 512 + kv * 64 +
                       ((sPos ^ (r1 & 7)) * 8);
  // V^T base: row h = ct*16 + col, key offset kt*64 + quad*8 (+32)
  const short* vBase = vtb + ((size_t)(b * 512 + kv * 64 + col)) * 2048 + quad * 8;

  const float SCALE = 0.125f * 1.44269504088896340736f;  // /sqrt(64) * log2e
  const int nkt = (qc >> 1) + 1;  // exact causal trip count (same all waves)

  // prologue: stage K tile 0 into buffer 0
  async_ld16(kRow0, &Ks[0][wave * 512]);
  async_ld16(kRow1, &Ks[0][2048 + wave * 512]);

  for (int kt = 0; kt < nkt; ++kt) {
    __syncthreads();  // vmcnt drained: tile kt resident in buf kt&1
    if (kt + 1 < nkt) {
      const int nb = (kt + 1) & 1;
      const size_t ko = (size_t)(kt + 1) * 64 * 512;
      async_ld16(kRow0 + ko, &Ks[nb][wave * 512]);
      async_ld16(kRow1 + ko, &Ks[nb][2048 + wave * 512]);
    }
    const int ktb = kt * 64;
    const short* ks = &Ks[kt & 1][0];

    // ---- V^T A-frags hoisted: latency hides under QK + softmax
    short8 vf[4][2];
#pragma unroll
    for (int ct = 0; ct < 4; ++ct) {
      const short* vp = vBase + (size_t)(ct * 16) * 2048 + ktb;
      vf[ct][0] = *(const short8*)(vp);
      vf[ct][1] = *(const short8*)(vp + 32);
    }

    // ---- K A-frags from LDS: A[m=mt*16+col][k=quad*8+j (+32kh)]
    short8 kf[4][2];
#pragma unroll
    for (int mt = 0; mt < 4; ++mt) {
      const int krow = mt * 16 + col;  // krow&7 == col&7
      kf[mt][0] = *(const short8*)(ks + krow * 64 + ((quad ^ (col & 7)) * 8));
      kf[mt][1] = *(const short8*)(ks + krow * 64 + (((4 + quad) ^ (col & 7)) * 8));
    }

#pragma unroll
    for (int nt = 0; nt < 2; ++nt) {
      const int rb = rb0 + nt * 16;

      f32x4 st[4];
#pragma unroll
      for (int mt = 0; mt < 4; ++mt) {
        f32x4 z = {0.f, 0.f, 0.f, 0.f};
        z = __builtin_amdgcn_mfma_f32_16x16x32_bf16(kf[mt][0], qf[nt][0], z, 0, 0, 0);
        z = __builtin_amdgcn_mfma_f32_16x16x32_bf16(kf[mt][1], qf[nt][1], z, 0, 0, 0);
        st[mt] = z;
      }

      if (ktb + 63 > rb) {  // diagonal overlap: per-score causal mask
        const int qrow = rb + col;
#pragma unroll
        for (int mt = 0; mt < 4; ++mt)
#pragma unroll
          for (int r = 0; r < 4; ++r)
            if (ktb + mt * 16 + quad * 4 + r > qrow) st[mt][r] = -1.0e30f;
      }

      // row max: in-lane tree + 3 independent xor-shuffles (one wait)
      float mx01 = fmaxf(fmaxf(st[0][0], st[0][1]), fmaxf(st[0][2], st[0][3]));
      float mx23 = fmaxf(fmaxf(st[1][0], st[1][1]), fmaxf(st[1][2], st[1][3]));
      float mx45 = fmaxf(fmaxf(st[2][0], st[2][1]), fmaxf(st[2][2], st[2][3]));
      float mx67 = fmaxf(fmaxf(st[3][0], st[3][1]), fmaxf(st[3][2], st[3][3]));
      float mx = fmaxf(fmaxf(mx01, mx23), fmaxf(mx45, mx67));
      {
        const float a = __shfl_xor(mx, 16, 64);
        const float d = __shfl_xor(mx, 32, 64);
        const float e = __shfl_xor(mx, 48, 64);
        mx = fmaxf(fmaxf(mx, a), fmaxf(d, e));
      }

      const float mn = fmaxf(mloc[nt], mx);
      const float alpha = exp2f((mloc[nt] - mn) * SCALE);
      mloc[nt] = mn;
      const float cc = mn * SCALE;

      float rs = 0.f;
#pragma unroll
      for (int mt = 0; mt < 4; ++mt)
#pragma unroll
        for (int r = 0; r < 4; ++r) {
          const float p = exp2f(st[mt][r] * SCALE - cc);
          st[mt][r] = p;
          rs += p;
        }
      {
        const float a = __shfl_xor(rs, 16, 64);
        const float d = __shfl_xor(rs, 32, 64);
        const float e = __shfl_xor(rs, 48, 64);
        rs = (rs + a) + (d + e);
      }
      lloc[nt] = lloc[nt] * alpha + rs;
#pragma unroll
      for (int ct = 0; ct < 4; ++ct)
#pragma unroll
        for (int r = 0; r < 4; ++r) oacc[nt][ct][r] *= alpha;

      // P write: keys mt*16+quad*4+{0..3} contiguous -> b64, chunk-swizzled
#pragma unroll
      for (int mt = 0; mt < 4; ++mt) {
        short4v w;
#pragma unroll
        for (int r = 0; r < 4; ++r) w[r] = f2bs(st[mt][r]);
        *(short4v*)(P + (nt * 16 + col) * 64 + (quad + 4 * (mt ^ (col & 3))) * 4) = w;
      }
    }

    asm volatile("s_waitcnt lgkmcnt(0)" ::: "memory");  // P visible wave-wide

    // P^T B-frags: B[k=key=quad*8+j (+32kh)][n=col]
    short8 pf[2][2];
#pragma unroll
    for (int nt = 0; nt < 2; ++nt) {
      const int base = (nt * 16 + col) * 64;
      pf[nt][0] = *(const short8*)(P + base + ((2 * quad) ^ swz) * 4);
      pf[nt][1] = *(const short8*)(P + base + ((8 + 2 * quad) ^ swz) * 4);
    }

    // PV accumulate with hoisted V frags
#pragma unroll
    for (int ct = 0; ct < 4; ++ct)
#pragma unroll
      for (int nt = 0; nt < 2; ++nt) {
        oacc[nt][ct] = __builtin_amdgcn_mfma_f32_16x16x32_bf16(
            vf[ct][0], pf[nt][0], oacc[nt][ct], 0, 0, 0);
        oacc[nt][ct] = __builtin_amdgcn_mfma_f32_16x16x32_bf16(
            vf[ct][1], pf[nt][1], oacc[nt][ct], 0, 0, 0);
      }
  }

  // ---- epilogue: O/l -> LDS (rows qlocal x 64 h) -> line-coalesced stores
  const float inv0 = 1.0f / lloc[0];
  const float inv1 = 1.0f / lloc[1];
#pragma unroll
  for (int nt = 0; nt < 2; ++nt) {
    const float inv = nt ? inv1 : inv0;
#pragma unroll
    for (int ct = 0; ct < 4; ++ct) {
      short4v w;
#pragma unroll
      for (int r = 0; r < 4; ++r) w[r] = f2bs(oacc[nt][ct][r] * inv);
      *(short4v*)(P + (nt * 16 + col) * 64 + ct * 16 + quad * 4) = w;
    }
  }
  asm volatile("s_waitcnt lgkmcnt(0)" ::: "memory");
  // 8 lanes x 16B cover one 128B output row; 64 lanes -> 8 rows per pass.
#pragma unroll
  for (int p = 0; p < 4; ++p) {
    const int qlocal = (lane >> 3) + 8 * p;
    const short8 row = *(const short8*)(P + qlocal * 64 + (lane & 7) * 8);
    *(short8*)(obuf + ((size_t)(b * 2048 + rb0 + qlocal)) * 2048 + hd * 64 +
               (lane & 7) * 8) = row;
  }
}

// ----------------------------------------------------------------------------
extern "C" void kernel_launch(void* const* d_in, const int* in_sizes, int n_in,
                              void* d_out, int out_size, void* d_ws,
                              size_t ws_size, hipStream_t stream) {
  char* ws = (char*)d_ws;
  int* flag = (int*)ws;              // [0,256): dtype flag
  short* rbuf = (short*)(ws + 256);  // [4096,2048] bf16
  short* wqb = rbuf + 8388608;       // [2048,2048]
  short* wkb = wqb + 4194304;        // [512,2048]
  short* wvb = wkb + 1048576;        // [512,2048]
  short* kbuf = wvb + 1048576;       // [4096,512]
  short* vbuf = kbuf + 2097152;      // [4096,512]
  short* abuf = vbuf + 2097152;      // [4096,2048]
  short* wot = abuf + 8388608;       // [2048,2048]
  short* vtb = wqb;                  // [2,512,2048] aliases spent W_Q copy
  short* qbuf = (short*)d_out;       // q scratch lives in d_out

  hipLaunchKernelGGL(detect_kernel, dim3(1), dim3(256), 0, stream,
                     (const short*)d_in[0], flag);
  hipLaunchKernelGGL(convert_kernel, dim3(7168), dim3(256), 0, stream,
                     d_in[0], d_in[1], d_in[2], d_in[3], rbuf, wqb, wkb, wvb,
                     flag);
  hipLaunchKernelGGL(qkv_gemm_kernel, dim3(24, 32), dim3(256), 0, stream,
                     rbuf, wqb, wkb, wvb, qbuf, kbuf, vbuf);
  hipLaunchKernelGGL(vt_kernel, dim3(8, 32, 2), dim3(256), 0, stream,
                     vbuf, vtb);
  hipLaunchKernelGGL(attn_kernel, dim3(16, 64), dim3(256), 0, stream,
                     qbuf, kbuf, vtb, abuf);
  hipLaunchKernelGGL(transpose_kernel, dim3(32, 32), dim3(256), 0, stream,
                     d_in[4], wot, flag);
  hipLaunchKernelGGL(out_gemm_kernel, dim3(16, 32), dim3(256), 0, stream,
                     abuf, wot, (void*)d_out, flag);
}

// Round 7
// 326.236 us; speedup vs baseline: 1.7644x; 1.7644x over previous
//
#include <hip/hip_runtime.h>

// ============================================================================
// Attention_14362370637857 on MI355X (gfx950).
// B=2, S=2048, D_MODEL=2048, NH=32, NKV=8 (GQA rep=4), DH=64.
//
// Pipeline:
//   1) detect_kernel   : dtype sniff (bf16 vs f32 inputs) -> flag
//   2) convert_kernel  : residual,W_Q,W_K,W_V -> canonical bf16 in ws
//   3) qkv_gemm_kernel : R[4096,2048] x W^T -> q (in d_out), k, v
//   4) vt_kernel       : v [b,p,h] -> vT [b,h,p]
//   5) attn_kernel v7  : causal flash attention, GQA kv-group blocks,
//                        K AND V LDS-staged (R3 memory + R6 scheduling)
//   6) transpose_kernel: W_O -> W_O^T (flag-aware read)
//   7) out_gemm_kernel : abuf x W_O^T -> d_out (bf16 or f32 per flag)
//
// attn v7 (one change vs v6): V^T staged in a double-buffered LDS tile via
// async_ld16 (same verified swizzle as K) and shared by all 4 waves —
// removes the 541 MB of per-wave redundant V global demand that made v6
// L2-miss-bound (FETCH 350 MB / WRITE 571 MB). LDS 48 KB -> 3 blocks/CU.
// ============================================================================

typedef __attribute__((ext_vector_type(8))) short short8;   // 8 bf16
typedef __attribute__((ext_vector_type(4))) short short4v;  // 4 bf16 = 8B
typedef __attribute__((ext_vector_type(4))) float f32x4;    // MFMA 16x16 C/D

__device__ __forceinline__ short f2bs(float f) {  // f32 -> bf16 bits, RNE
  unsigned u = __float_as_uint(f);
  u = (u + 0x7fffu + ((u >> 16) & 1u)) >> 16;
  return (short)u;
}
__device__ __forceinline__ float bs2f(short s) {  // bf16 bits -> f32
  return __uint_as_float(((unsigned)(unsigned short)s) << 16);
}

__device__ __forceinline__ void async_ld16(const void* g, void* l) {
  __builtin_amdgcn_global_load_lds((__attribute__((address_space(1))) void*)(g),
                                   (__attribute__((address_space(3))) void*)(l),
                                   16, 0, 0);
}

// ----------------------------------------------------------------------------
__global__ __launch_bounds__(256) void detect_kernel(const short* __restrict__ r,
                                                     int* __restrict__ flag) {
  __shared__ int bad;
  if (threadIdx.x == 0) bad = 0;
  __syncthreads();
  int mybad = 0;
#pragma unroll
  for (int i = 0; i < 16; ++i) {
    float x = bs2f(r[threadIdx.x + i * 256]);
    if (!(fabsf(x) < 100.0f)) mybad = 1;
  }
  if (mybad) atomicOr(&bad, 1);
  __syncthreads();
  if (threadIdx.x == 0) *flag = bad;
}

// ----------------------------------------------------------------------------
__global__ __launch_bounds__(256) void convert_kernel(
    const void* __restrict__ s0, const void* __restrict__ s1,
    const void* __restrict__ s2, const void* __restrict__ s3,
    short* __restrict__ d0, short* __restrict__ d1, short* __restrict__ d2,
    short* __restrict__ d3, const int* __restrict__ flag) {
  long off = (long)blockIdx.x * 256 + threadIdx.x;
  const void* src;
  short* dst;
  if (off < 1048576) {
    src = s0; dst = d0;
  } else if ((off -= 1048576) < 524288) {
    src = s1; dst = d1;
  } else if ((off -= 524288) < 131072) {
    src = s2; dst = d2;
  } else {
    off -= 131072; src = s3; dst = d3;
  }
  const long e = off * 8;
  short8 v;
  if (*flag) {
    const float* f = (const float*)src + e;
    const f32x4 a = *(const f32x4*)(f);
    const f32x4 b = *(const f32x4*)(f + 4);
#pragma unroll
    for (int j = 0; j < 4; ++j) {
      v[j] = f2bs(a[j]);
      v[4 + j] = f2bs(b[j]);
    }
  } else {
    v = *(const short8*)((const short*)src + e);
  }
  *(short8*)(dst + e) = v;
}

// ----------------------------------------------------------------------------
// C[M,N] = A[M,K] * B[N,K]^T (row-major bf16), 128x128 tile, BK=32.
// ----------------------------------------------------------------------------
__device__ __forceinline__ void gemm128(const short* __restrict__ A, int lda,
                                        const short* __restrict__ B, int ldb,
                                        void* __restrict__ C, int ldc,
                                        int rowBase, int colBase, int K,
                                        short* As, short* Bs, int outF32) {
  const int t = threadIdx.x;
  const int wave = t >> 6;
  const int lane = t & 63;
  const int quad = lane >> 4;
  const int m16 = lane & 15;
  const int sRow = t >> 2;
  const int sOff = (t & 3) * 8;
  const int wr = (wave >> 1) * 64;
  const int wc = (wave & 1) * 64;

  const short* A0 = A + (size_t)(rowBase + sRow) * lda + sOff;
  const short* A1 = A0 + (size_t)64 * lda;
  const short* B0 = B + (size_t)(colBase + sRow) * ldb + sOff;
  const short* B1 = B0 + (size_t)64 * ldb;

  short* ldsA0 = As + wave * 512;
  short* ldsA1 = As + 2048 + wave * 512;
  short* ldsB0 = Bs + wave * 512;
  short* ldsB1 = Bs + 2048 + wave * 512;

  f32x4 acc[4][4] = {};

  const int nK = K >> 5;
  for (int kt = 0; kt < nK; ++kt) {
    __syncthreads();
    const int ko = kt * 32;
    async_ld16(A0 + ko, ldsA0);
    async_ld16(A1 + ko, ldsA1);
    async_ld16(B0 + ko, ldsB0);
    async_ld16(B1 + ko, ldsB1);
    __syncthreads();

    short8 af[4], bfr[4];
#pragma unroll
    for (int i = 0; i < 4; ++i)
      af[i] = *(const short8*)(As + (wr + i * 16 + m16) * 32 + quad * 8);
#pragma unroll
    for (int i = 0; i < 4; ++i)
      bfr[i] = *(const short8*)(Bs + (wc + i * 16 + m16) * 32 + quad * 8);
#pragma unroll
    for (int i = 0; i < 4; ++i)
#pragma unroll
      for (int j = 0; j < 4; ++j)
        acc[i][j] = __builtin_amdgcn_mfma_f32_16x16x32_bf16(af[i], bfr[j],
                                                            acc[i][j], 0, 0, 0);
  }

#pragma unroll
  for (int i = 0; i < 4; ++i)
#pragma unroll
    for (int j = 0; j < 4; ++j)
#pragma unroll
      for (int r = 0; r < 4; ++r) {
        const int row = rowBase + wr + i * 16 + quad * 4 + r;
        const int col = colBase + wc + j * 16 + m16;
        const size_t idx = (size_t)row * ldc + col;
        if (outF32)
          ((float*)C)[idx] = acc[i][j][r];
        else
          ((short*)C)[idx] = f2bs(acc[i][j][r]);
      }
}

__global__ __launch_bounds__(256) void qkv_gemm_kernel(
    const short* __restrict__ R, const short* __restrict__ WQ,
    const short* __restrict__ WK, const short* __restrict__ WV,
    short* __restrict__ q, short* __restrict__ k, short* __restrict__ v) {
  __shared__ __align__(16) short As[128 * 32];
  __shared__ __align__(16) short Bs[128 * 32];
  const int ct = blockIdx.x;
  const int rowBase = blockIdx.y * 128;
  const short* B;
  short* C;
  int colBase, ldc;
  if (ct < 16) {
    B = WQ; C = q; colBase = ct * 128; ldc = 2048;
  } else if (ct < 20) {
    B = WK; C = k; colBase = (ct - 16) * 128; ldc = 512;
  } else {
    B = WV; C = v; colBase = (ct - 20) * 128; ldc = 512;
  }
  gemm128(R, 2048, B, 2048, C, ldc, rowBase, colBase, 2048, As, Bs, 0);
}

__global__ __launch_bounds__(256) void out_gemm_kernel(
    const short* __restrict__ A, const short* __restrict__ Bt,
    void* __restrict__ C, const int* __restrict__ flag) {
  __shared__ __align__(16) short As[128 * 32];
  __shared__ __align__(16) short Bs[128 * 32];
  const int outF32 = *flag;
  gemm128(A, 2048, Bt, 2048, C, 2048, blockIdx.y * 128, blockIdx.x * 128, 2048,
          As, Bs, outF32);
}

// ----------------------------------------------------------------------------
// W_O [2048,2048] -> W_O^T, flag-aware source dtype.
// ----------------------------------------------------------------------------
__global__ __launch_bounds__(256) void transpose_kernel(
    const void* __restrict__ in, short* __restrict__ out,
    const int* __restrict__ flag) {
  __shared__ short tile[64][65];
  const int bx = blockIdx.x, by = blockIdx.y;
  const int tx = threadIdx.x & 63, ty = threadIdx.x >> 6;
  const int isf = *flag;
#pragma unroll
  for (int i = 0; i < 16; ++i) {
    const int r = ty + i * 4;
    const size_t idx = (size_t)(by * 64 + r) * 2048 + bx * 64 + tx;
    tile[r][tx] = isf ? f2bs(((const float*)in)[idx]) : ((const short*)in)[idx];
  }
  __syncthreads();
#pragma unroll
  for (int i = 0; i < 16; ++i) {
    const int r = ty + i * 4;
    out[(size_t)(bx * 64 + r) * 2048 + by * 64 + tx] = tile[tx][r];
  }
}

// ----------------------------------------------------------------------------
// v [2,2048,512] -> vT [2,512,2048]
// ----------------------------------------------------------------------------
__global__ __launch_bounds__(256) void vt_kernel(const short* __restrict__ v,
                                                 short* __restrict__ vt) {
  __shared__ short tile[64][65];
  const int hb = blockIdx.x * 64, pb = blockIdx.y * 64, b = blockIdx.z;
  const int tx = threadIdx.x & 63, ty = threadIdx.x >> 6;
#pragma unroll
  for (int i = 0; i < 16; ++i) {
    const int r = ty + i * 4;
    tile[r][tx] = v[((size_t)(b * 2048 + pb + r)) * 512 + hb + tx];
  }
  __syncthreads();
#pragma unroll
  for (int i = 0; i < 16; ++i) {
    const int r = ty + i * 4;
    vt[((size_t)(b * 512 + hb + r)) * 2048 + pb + tx] = tile[tx][r];
  }
}

// ----------------------------------------------------------------------------
// Causal flash attention v7: GQA kv-group blocks, K AND V LDS-staged.
// Grid (16, 64): x = b*8+kv, y -> qc = 63-y (long-first).
// Block = 4 waves = the 4 q-heads of one kv group over the SAME 32 q-rows.
// K and V^T tiles double-buffered in LDS via async_ld16 (one barrier/iter,
// prefetch issued right after the barrier, consumed next iter). Per tile:
//   S^T[key][qrow] = K(A-frags, LDS) x Q^T(B-frags, regs)
//   O^T[h][qrow]  += V^T(A-frags, LDS) x P^T(B-frags via LDS transit)
// LDS = 16K (K dbuf) + 16K (V dbuf) + 16K (P) = 48 KB -> 3 blocks/CU.
// ----------------------------------------------------------------------------
__global__ __launch_bounds__(256, 3) void attn_kernel(
    const short* __restrict__ qbuf, const short* __restrict__ kbuf,
    const short* __restrict__ vtb, short* __restrict__ obuf) {
  __shared__ __align__(16) short Ks[2][64 * 64];  // 16 KB K double-buffer
  __shared__ __align__(16) short Vs[2][64 * 64];  // 16 KB V^T double-buffer
  __shared__ __align__(16) short Pb[4][32 * 64];  // 16 KB per-wave P transit

  const int b = blockIdx.x >> 3;
  const int kv = blockIdx.x & 7;
  const int qc = 63 - blockIdx.y;  // long-first dispatch
  const int t = threadIdx.x;
  const int wave = t >> 6;
  const int hd = kv * 4 + wave;
  const int lane = t & 63;
  const int quad = lane >> 4;
  const int col = lane & 15;
  const int rb0 = qc * 32;

  // Q B-frags: B[k=quad*8+j (+32*kh)][n=col] = Q[qrow][h]
  short8 qf[2][2];
#pragma unroll
  for (int nt = 0; nt < 2; ++nt) {
    const int qr = rb0 + nt * 16 + col;
    const short* qp = qbuf + ((size_t)(b * 2048 + qr)) * 2048 + hd * 64 + quad * 8;
    qf[nt][0] = *(const short8*)(qp);
    qf[nt][1] = *(const short8*)(qp + 32);
  }

  float mloc[2] = {-3.0e38f, -3.0e38f};
  float lloc[2] = {0.f, 0.f};
  f32x4 oacc[2][4] = {};

  short* P = &Pb[wave][0];
  const int swz = 4 * (col & 3);  // P chunk swizzle

  // Staging (R3-verified): thread t covers rows t>>3 and +32, chunk t&7;
  // LDS row r chunk c holds global chunk c^(r&7).
  const int sRow = t >> 3;
  const int sPos = t & 7;
  const int r1 = sRow + 32;
  const short* kRow0 = kbuf + ((size_t)(b * 2048 + sRow)) * 512 + kv * 64 +
                       ((sPos ^ (sRow & 7)) * 8);
  const short* kRow1 = kbuf + ((size_t)(b * 2048 + r1)) * 512 + kv * 64 +
                       ((sPos ^ (r1 & 7)) * 8);
  const short* vRow0 = vtb + ((size_t)(b * 512 + kv * 64 + sRow)) * 2048 +
                       ((sPos ^ (sRow & 7)) * 8);
  const short* vRow1 = vtb + ((size_t)(b * 512 + kv * 64 + r1)) * 2048 +
                       ((sPos ^ (r1 & 7)) * 8);

  const float SCALE = 0.125f * 1.44269504088896340736f;  // /sqrt(64) * log2e
  const int nkt = (qc >> 1) + 1;  // exact causal trip count (same all waves)

  // prologue: stage K/V tile 0 into buffer 0
  async_ld16(kRow0, &Ks[0][wave * 512]);
  async_ld16(kRow1, &Ks[0][2048 + wave * 512]);
  async_ld16(vRow0, &Vs[0][wave * 512]);
  async_ld16(vRow1, &Vs[0][2048 + wave * 512]);

  for (int kt = 0; kt < nkt; ++kt) {
    __syncthreads();  // vmcnt drained: tile kt resident in buf kt&1
    if (kt + 1 < nkt) {
      const int nb = (kt + 1) & 1;
      const size_t ko = (size_t)(kt + 1) * 64 * 512;  // K: 64 rows ahead
      const int vo = (kt + 1) * 64;                   // V^T: 64 keys ahead
      async_ld16(kRow0 + ko, &Ks[nb][wave * 512]);
      async_ld16(kRow1 + ko, &Ks[nb][2048 + wave * 512]);
      async_ld16(vRow0 + vo, &Vs[nb][wave * 512]);
      async_ld16(vRow1 + vo, &Vs[nb][2048 + wave * 512]);
    }
    const int ktb = kt * 64;
    const short* ks = &Ks[kt & 1][0];
    const short* vs = &Vs[kt & 1][0];

    // ---- K A-frags from LDS: A[m=mt*16+col][k=quad*8+j (+32kh)]
    short8 kf[4][2];
#pragma unroll
    for (int mt = 0; mt < 4; ++mt) {
      const int krow = mt * 16 + col;  // krow&7 == col&7
      kf[mt][0] = *(const short8*)(ks + krow * 64 + ((quad ^ (col & 7)) * 8));
      kf[mt][1] = *(const short8*)(ks + krow * 64 + (((4 + quad) ^ (col & 7)) * 8));
    }

#pragma unroll
    for (int nt = 0; nt < 2; ++nt) {
      const int rb = rb0 + nt * 16;

      f32x4 st[4];
#pragma unroll
      for (int mt = 0; mt < 4; ++mt) {
        f32x4 z = {0.f, 0.f, 0.f, 0.f};
        z = __builtin_amdgcn_mfma_f32_16x16x32_bf16(kf[mt][0], qf[nt][0], z, 0, 0, 0);
        z = __builtin_amdgcn_mfma_f32_16x16x32_bf16(kf[mt][1], qf[nt][1], z, 0, 0, 0);
        st[mt] = z;
      }

      if (ktb + 63 > rb) {  // diagonal overlap: per-score causal mask
        const int qrow = rb + col;
#pragma unroll
        for (int mt = 0; mt < 4; ++mt)
#pragma unroll
          for (int r = 0; r < 4; ++r)
            if (ktb + mt * 16 + quad * 4 + r > qrow) st[mt][r] = -1.0e30f;
      }

      // row max: in-lane tree + 3 independent xor-shuffles (one wait)
      float mx01 = fmaxf(fmaxf(st[0][0], st[0][1]), fmaxf(st[0][2], st[0][3]));
      float mx23 = fmaxf(fmaxf(st[1][0], st[1][1]), fmaxf(st[1][2], st[1][3]));
      float mx45 = fmaxf(fmaxf(st[2][0], st[2][1]), fmaxf(st[2][2], st[2][3]));
      float mx67 = fmaxf(fmaxf(st[3][0], st[3][1]), fmaxf(st[3][2], st[3][3]));
      float mx = fmaxf(fmaxf(mx01, mx23), fmaxf(mx45, mx67));
      {
        const float a = __shfl_xor(mx, 16, 64);
        const float d = __shfl_xor(mx, 32, 64);
        const float e = __shfl_xor(mx, 48, 64);
        mx = fmaxf(fmaxf(mx, a), fmaxf(d, e));
      }

      const float mn = fmaxf(mloc[nt], mx);
      const float alpha = exp2f((mloc[nt] - mn) * SCALE);
      mloc[nt] = mn;
      const float cc = mn * SCALE;

      float rs = 0.f;
#pragma unroll
      for (int mt = 0; mt < 4; ++mt)
#pragma unroll
        for (int r = 0; r < 4; ++r) {
          const float p = exp2f(st[mt][r] * SCALE - cc);
          st[mt][r] = p;
          rs += p;
        }
      {
        const float a = __shfl_xor(rs, 16, 64);
        const float d = __shfl_xor(rs, 32, 64);
        const float e = __shfl_xor(rs, 48, 64);
        rs = (rs + a) + (d + e);
      }
      lloc[nt] = lloc[nt] * alpha + rs;
#pragma unroll
      for (int ct = 0; ct < 4; ++ct)
#pragma unroll
        for (int r = 0; r < 4; ++r) oacc[nt][ct][r] *= alpha;

      // P write: keys mt*16+quad*4+{0..3} contiguous -> b64, chunk-swizzled
#pragma unroll
      for (int mt = 0; mt < 4; ++mt) {
        short4v w;
#pragma unroll
        for (int r = 0; r < 4; ++r) w[r] = f2bs(st[mt][r]);
        *(short4v*)(P + (nt * 16 + col) * 64 + (quad + 4 * (mt ^ (col & 3))) * 4) = w;
      }
    }

    asm volatile("s_waitcnt lgkmcnt(0)" ::: "memory");  // P visible wave-wide

    // P^T B-frags: B[k=key=quad*8+j (+32kh)][n=col]
    short8 pf[2][2];
#pragma unroll
    for (int nt = 0; nt < 2; ++nt) {
      const int base = (nt * 16 + col) * 64;
      pf[nt][0] = *(const short8*)(P + base + ((2 * quad) ^ swz) * 4);
      pf[nt][1] = *(const short8*)(P + base + ((8 + 2 * quad) ^ swz) * 4);
    }

    // ---- V^T A-frags from LDS + PV accumulate
#pragma unroll
    for (int ct = 0; ct < 4; ++ct) {
      const int h = ct * 16 + col;  // h&7 == col&7
      const short8 va = *(const short8*)(vs + h * 64 + ((quad ^ (col & 7)) * 8));
      const short8 vb = *(const short8*)(vs + h * 64 + (((4 + quad) ^ (col & 7)) * 8));
#pragma unroll
      for (int nt = 0; nt < 2; ++nt) {
        oacc[nt][ct] = __builtin_amdgcn_mfma_f32_16x16x32_bf16(
            va, pf[nt][0], oacc[nt][ct], 0, 0, 0);
        oacc[nt][ct] = __builtin_amdgcn_mfma_f32_16x16x32_bf16(
            vb, pf[nt][1], oacc[nt][ct], 0, 0, 0);
      }
    }
  }

  // ---- epilogue: O/l -> LDS (rows qlocal x 64 h) -> line-coalesced stores
  const float inv0 = 1.0f / lloc[0];
  const float inv1 = 1.0f / lloc[1];
#pragma unroll
  for (int nt = 0; nt < 2; ++nt) {
    const float inv = nt ? inv1 : inv0;
#pragma unroll
    for (int ct = 0; ct < 4; ++ct) {
      short4v w;
#pragma unroll
      for (int r = 0; r < 4; ++r) w[r] = f2bs(oacc[nt][ct][r] * inv);
      *(short4v*)(P + (nt * 16 + col) * 64 + ct * 16 + quad * 4) = w;
    }
  }
  asm volatile("s_waitcnt lgkmcnt(0)" ::: "memory");
  // 8 lanes x 16B cover one 128B output row; 64 lanes -> 8 rows per pass.
#pragma unroll
  for (int p = 0; p < 4; ++p) {
    const int qlocal = (lane >> 3) + 8 * p;
    const short8 row = *(const short8*)(P + qlocal * 64 + (lane & 7) * 8);
    *(short8*)(obuf + ((size_t)(b * 2048 + rb0 + qlocal)) * 2048 + hd * 64 +
               (lane & 7) * 8) = row;
  }
}

// ----------------------------------------------------------------------------
extern "C" void kernel_launch(void* const* d_in, const int* in_sizes, int n_in,
                              void* d_out, int out_size, void* d_ws,
                              size_t ws_size, hipStream_t stream) {
  char* ws = (char*)d_ws;
  int* flag = (int*)ws;              // [0,256): dtype flag
  short* rbuf = (short*)(ws + 256);  // [4096,2048] bf16
  short* wqb = rbuf + 8388608;       // [2048,2048]
  short* wkb = wqb + 4194304;        // [512,2048]
  short* wvb = wkb + 1048576;        // [512,2048]
  short* kbuf = wvb + 1048576;       // [4096,512]
  short* vbuf = kbuf + 2097152;      // [4096,512]
  short* abuf = vbuf + 2097152;      // [4096,2048]
  short* wot = abuf + 8388608;       // [2048,2048]
  short* vtb = wqb;                  // [2,512,2048] aliases spent W_Q copy
  short* qbuf = (short*)d_out;       // q scratch lives in d_out

  hipLaunchKernelGGL(detect_kernel, dim3(1), dim3(256), 0, stream,
                     (const short*)d_in[0], flag);
  hipLaunchKernelGGL(convert_kernel, dim3(7168), dim3(256), 0, stream,
                     d_in[0], d_in[1], d_in[2], d_in[3], rbuf, wqb, wkb, wvb,
                     flag);
  hipLaunchKernelGGL(qkv_gemm_kernel, dim3(24, 32), dim3(256), 0, stream,
                     rbuf, wqb, wkb, wvb, qbuf, kbuf, vbuf);
  hipLaunchKernelGGL(vt_kernel, dim3(8, 32, 2), dim3(256), 0, stream,
                     vbuf, vtb);
  hipLaunchKernelGGL(attn_kernel, dim3(16, 64), dim3(256), 0, stream,
                     qbuf, kbuf, vtb, abuf);
  hipLaunchKernelGGL(transpose_kernel, dim3(32, 32), dim3(256), 0, stream,
                     d_in[4], wot, flag);
  hipLaunchKernelGGL(out_gemm_kernel, dim3(16, 32), dim3(256), 0, stream,
                     abuf, wot, (void*)d_out, flag);
}